// Round 9
// baseline (67.210 us; speedup 1.0000x reference)
//
#include <hip/hip_runtime.h>
#include <math.h>

#define FRAME_LEN 512
#define HOP       256
#define NFREQ     257
#define NFREQ_PAD 288
#define NBATCH    64
#define NSAMP     160000
#define TFRAMES   624
#define EPS       1.1920928955078125e-07f

#define MT 256                 // frames per tile; 156 M-tiles
#define FT 32                  // freq bins per tile
#define BK 32                  // K chunk (1 kstep) -> 40KB LDS, 4 blocks/CU
#define NK (FRAME_LEN / BK)    // 16 K-iterations
#define XBLKS 5000

#define ASZ (MT * BK)          // shorts per A buffer (8192)
#define BSZ (2 * FT * BK)      // shorts per B buffer (2048)

typedef __attribute__((ext_vector_type(8))) short short8;   // 8 bf16
typedef __attribute__((ext_vector_type(4))) float f32x4;    // MFMA acc

static __device__ __forceinline__ unsigned int f2bf(float f) {
    unsigned int u = __float_as_uint(f);
    return (u + 0x7fffu + ((u >> 16) & 1u)) >> 16;          // RNE to bf16
}
static __device__ __forceinline__ uint4 pack8(float4 a, float4 b) {
    uint4 r;
    r.x = f2bf(a.x) | (f2bf(a.y) << 16);
    r.y = f2bf(a.z) | (f2bf(a.w) << 16);
    r.z = f2bf(b.x) | (f2bf(b.y) << 16);
    r.w = f2bf(b.z) | (f2bf(b.w) << 16);
    return r;
}
static __device__ __forceinline__ void gload_lds16(const void* g, void* l) {
    __builtin_amdgcn_global_load_lds(
        (const __attribute__((address_space(1))) void*)g,
        (__attribute__((address_space(3))) void*)l, 16, 0, 0);
}

// ------------------------------------------------- prep: tables + x->bf16 ---
__global__ __launch_bounds__(256) void prep(const float* __restrict__ x,
                                            unsigned short* __restrict__ xbf,
                                            unsigned short* __restrict__ Wc,
                                            unsigned short* __restrict__ Ws) {
    if (blockIdx.x < XBLKS) {                   // x -> bf16, 8 elems/thread
        int i = blockIdx.x * 256 + threadIdx.x;
        const float4* src = (const float4*)x + (size_t)i * 2;
        float4 a = src[0], b = src[1];
        *(uint4*)(xbf + (size_t)i * 8) = pack8(a, b);
    } else {                                    // DFT tables, bf16, 288 rows
        int f = blockIdx.x - XBLKS;             // 0..287
        for (int n = threadIdx.x; n < FRAME_LEN; n += 256) {
            unsigned short c = 0, s = 0;
            if (f < NFREQ) {
                float w = 0.5f * (1.0f - cosf(2.0f * (float)M_PI * (float)n / (float)FRAME_LEN));
                int r = (f * n) & (FRAME_LEN - 1);
                float ang = (float)r * (2.0f * (float)M_PI / (float)FRAME_LEN);
                float sv, cv;
                sincosf(ang, &sv, &cv);
                c = (unsigned short)f2bf(cv * w);
                s = (unsigned short)f2bf(sv * w);   // i = +sin*w
            }
            Wc[f * FRAME_LEN + n] = c;
            Ws[f * FRAME_LEN + n] = s;
        }
    }
}

// -------- stft via bf16 MFMA: MT=256 / mf=4 / BK=32, 2-buffer, 40KB LDS -----
__global__ __launch_bounds__(256) void stft_mfma(
    const unsigned short* __restrict__ xbf, const unsigned short* __restrict__ Wc,
    const unsigned short* __restrict__ Ws, float* __restrict__ mag)
{
    __shared__ unsigned short As[2][MT][BK];    // 32 KB, linear gload dest
    __shared__ unsigned short Bs[2][2][FT][BK]; // 8 KB (cos, sin)

    const int tid = threadIdx.x;
    // Bijective XCD swizzle (m204): nwg=1404, q=175, r=4.
    // 9 consecutive logical ids (same A-tile) land on one XCD L2.
    const int xcd = blockIdx.x & 7;
    const int slot = blockIdx.x >> 3;
    const int logical = (xcd < 4 ? xcd * 176 : 704 + (xcd - 4) * 175) + slot;
    const int tileM = logical / 9;              // 0..155
    const int tileF = logical % 9;              // 0..8
    const int wid = tid >> 6;
    const int lane = tid & 63;
    const int lrow = lane & 15;
    const int lhi = lane >> 4;

    unsigned short* AsB = &As[0][0][0];
    unsigned short* BsB = &Bs[0][0][0][0];

    // k0-invariant per-lane staging sources; chunk-XOR swizzle on SOURCE
    // (dest linear for gload_lds; read applies the same XOR). X(r)=(r>>1)&3
    // gives worst-case 2-way bank aliasing on the b128 frag reads (free).
    const unsigned short* pA[4];
    #pragma unroll
    for (int j = 0; j < 4; j++) {
        int s = j * 256 + tid;                  // slot 0..1023
        int r = s >> 2;                         // row 0..255
        int c = s & 3;                          // 16B chunk 0..3
        int m = tileM * MT + r;                 // < 39936 exact
        int b = m / TFRAMES;
        int t = m - b * TFRAMES;
        int co = c ^ ((r >> 1) & 3);
        pA[j] = xbf + (size_t)b * NSAMP + t * HOP + co * 8;
    }
    const unsigned short* pB;
    {
        int tbl = tid >> 7;                     // 0 cos, 1 sin
        int fr = (tid >> 2) & 31;
        int c = tid & 3;
        int co = c ^ ((fr >> 1) & 3);
        const unsigned short* tb = tbl ? Ws : Wc;
        pB = tb + (tileF * FT + fr) * FRAME_LEN + co * 8;   // rows < 288 padded
    }

    f32x4 accr[4][2] = {};
    f32x4 acci[4][2] = {};

    // ---- prologue: stage chunk 0 into buf 0
    #pragma unroll
    for (int j = 0; j < 4; j++)
        gload_lds16(pA[j], AsB + j * 2048 + wid * 512);
    gload_lds16(pB, BsB + wid * 512);
    __syncthreads();

    int buf = 0;
    #pragma unroll
    for (int it = 0; it < NK; it++) {
        // ---- issue next-chunk loads into other buffer (overlap with compute)
        if (it < NK - 1) {
            const int k0 = (it + 1) * BK;
            #pragma unroll
            for (int j = 0; j < 4; j++)
                gload_lds16(pA[j] + k0, AsB + (buf ^ 1) * ASZ + j * 2048 + wid * 512);
            gload_lds16(pB + k0, BsB + (buf ^ 1) * BSZ + wid * 512);
        }
        // ---- compute current buffer: wave owns rows wid*64 .. wid*64+63
        {
            const int ci = lhi ^ ((lrow >> 1) & 3);
            short8 a[4], bc[2], bsn[2];
            #pragma unroll
            for (int mf = 0; mf < 4; mf++)
                a[mf] = *(const short8*)(AsB + buf * ASZ +
                    (wid * 64 + mf * 16 + lrow) * BK + ci * 8);
            #pragma unroll
            for (int nf = 0; nf < 2; nf++) {
                bc[nf]  = *(const short8*)(BsB + buf * BSZ +
                    (nf * 16 + lrow) * BK + ci * 8);
                bsn[nf] = *(const short8*)(BsB + buf * BSZ + FT * BK +
                    (nf * 16 + lrow) * BK + ci * 8);
            }
            #pragma unroll
            for (int mf = 0; mf < 4; mf++) {
                #pragma unroll
                for (int nf = 0; nf < 2; nf++) {
                    accr[mf][nf] = __builtin_amdgcn_mfma_f32_16x16x32_bf16(
                        a[mf], bc[nf], accr[mf][nf], 0, 0, 0);
                    acci[mf][nf] = __builtin_amdgcn_mfma_f32_16x16x32_bf16(
                        a[mf], bsn[nf], acci[mf][nf], 0, 0, 0);
                }
            }
        }
        __syncthreads();   // next buffer's loads landed; prior reads done
        buf ^= 1;
    }

    // ---- epilogue: mag = sqrt(r^2 + i^2), float4 over 4 consecutive t
    #pragma unroll
    for (int mf = 0; mf < 4; mf++) {
        int m0 = tileM * MT + wid * 64 + mf * 16 + lhi * 4;
        int b = m0 / TFRAMES;
        int t = m0 - b * TFRAMES;               // %4==0, run stays in batch
        #pragma unroll
        for (int nf = 0; nf < 2; nf++) {
            int f = tileF * FT + nf * 16 + lrow;
            if (f < NFREQ) {
                float4 o;
                o.x = sqrtf(accr[mf][nf][0] * accr[mf][nf][0] + acci[mf][nf][0] * acci[mf][nf][0]);
                o.y = sqrtf(accr[mf][nf][1] * accr[mf][nf][1] + acci[mf][nf][1] * acci[mf][nf][1]);
                o.z = sqrtf(accr[mf][nf][2] * accr[mf][nf][2] + acci[mf][nf][2] * acci[mf][nf][2]);
                o.w = sqrtf(accr[mf][nf][3] * accr[mf][nf][3] + acci[mf][nf][3] * acci[mf][nf][3]);
                *(float4*)(mag + ((size_t)b * NFREQ + f) * TFRAMES + t) = o;
            }
        }
    }
}

// ------------------------------------------- normalize: warp-per-row, f4 ----
__global__ __launch_bounds__(256) void normalize(const float* __restrict__ mag,
                                                 float* __restrict__ feat)
{
    const int row = blockIdx.x * 4 + (threadIdx.x >> 6);    // b*NFREQ+f
    const int lane = threadIdx.x & 63;
    const float* mp = mag + (size_t)row * TFRAMES;

    float4 v[3];
    float sum = 0.f;
    #pragma unroll
    for (int i = 0; i < 3; i++) {
        int c4 = lane + i * 64;                 // 156 float4 per row
        if (c4 < TFRAMES / 4) {
            float4 t = *(const float4*)(mp + c4 * 4);
            t.x = fmaxf(t.x, EPS); t.y = fmaxf(t.y, EPS);
            t.z = fmaxf(t.z, EPS); t.w = fmaxf(t.w, EPS);
            v[i] = t;
            sum += (t.x + t.y) + (t.z + t.w);
        } else {
            v[i] = make_float4(0.f, 0.f, 0.f, 0.f);
        }
    }
    #pragma unroll
    for (int off = 1; off < 64; off <<= 1) sum += __shfl_xor(sum, off, 64);
    const float mean = sum * (1.0f / (float)TFRAMES);

    float ssd = 0.f;
    #pragma unroll
    for (int i = 0; i < 3; i++) {
        int c4 = lane + i * 64;
        if (c4 < TFRAMES / 4) {
            float dx = v[i].x - mean, dy = v[i].y - mean;
            float dz = v[i].z - mean, dw = v[i].w - mean;
            ssd += (dx * dx + dy * dy) + (dz * dz + dw * dw);
        }
    }
    #pragma unroll
    for (int off = 1; off < 64; off <<= 1) ssd += __shfl_xor(ssd, off, 64);
    const float stdv = sqrtf(ssd * (1.0f / (float)(TFRAMES - 1)));
    const float inv = 1.0f / (stdv + EPS);

    float* fp = feat + (size_t)row * TFRAMES;
    #pragma unroll
    for (int i = 0; i < 3; i++) {
        int c4 = lane + i * 64;
        if (c4 < TFRAMES / 4) {
            float4 o;
            o.x = (v[i].x - mean) * inv; o.y = (v[i].y - mean) * inv;
            o.z = (v[i].z - mean) * inv; o.w = (v[i].w - mean) * inv;
            *(float4*)(fp + c4 * 4) = o;
        }
    }
}

// ---------------------------------------------------------------- launch ----
extern "C" void kernel_launch(void* const* d_in, const int* in_sizes, int n_in,
                              void* d_out, int out_size, void* d_ws, size_t ws_size,
                              hipStream_t stream) {
    const float* x = (const float*)d_in[0];
    unsigned short* Wc  = (unsigned short*)d_ws;            // 288*512 bf16
    unsigned short* Ws  = Wc + NFREQ_PAD * FRAME_LEN;       // 288*512 bf16
    unsigned short* xbf = Ws + NFREQ_PAD * FRAME_LEN;       // 64*160000 bf16
    float* mag  = (float*)d_out;                            // [64][257][624]
    float* feat = mag + (size_t)NBATCH * NFREQ * TFRAMES;

    prep<<<XBLKS + NFREQ_PAD, 256, 0, stream>>>(x, xbf, Wc, Ws);

    // 156 M-tiles x 9 F-tiles, linearized + XCD-swizzled in-kernel
    stft_mfma<<<156 * 9, 256, 0, stream>>>(xbf, Wc, Ws, mag);

    normalize<<<NBATCH * NFREQ / 4, 256, 0, stream>>>(mag, feat);
}

// Round 10
// 54.397 us; speedup vs baseline: 1.2356x; 1.2356x over previous
//
#include <hip/hip_runtime.h>
#include <math.h>

#define FRAME_LEN 512
#define HOP       256
#define NFREQ     257
#define NBATCH    64
#define NSAMP     160000
#define NSAMPH    80000        // per parity array
#define TFRAMES   624
#define EPS       1.1920928955078125e-07f

#define MT 128                 // frames per tile; 312 M-tiles
#define FT 32                  // freq bins per tile; 5 f-tiles (f 0..128 pad 160)
#define BK 64                  // K chunk per stage
#define KH 256                 // K per parity
#define XBLKS 5000

#define ASZ (MT * BK)          // shorts per A buffer (8192)
#define BSZ (2 * FT * BK)      // shorts per B buffer (4096)

typedef __attribute__((ext_vector_type(8))) short short8;   // 8 bf16
typedef __attribute__((ext_vector_type(4))) float f32x4;    // MFMA acc

static __device__ __forceinline__ unsigned int f2bf(float f) {
    unsigned int u = __float_as_uint(f);
    return (u + 0x7fffu + ((u >> 16) & 1u)) >> 16;          // RNE to bf16
}
static __device__ __forceinline__ void gload_lds16(const void* g, void* l) {
    __builtin_amdgcn_global_load_lds(
        (const __attribute__((address_space(1))) void*)g,
        (__attribute__((address_space(3))) void*)l, 16, 0, 0);
}

// ---------------- prep: de-interleave x -> bf16 xe/xo + 4 parity tables -----
__global__ __launch_bounds__(256) void prep(const float* __restrict__ x,
                                            unsigned short* __restrict__ xe,
                                            unsigned short* __restrict__ xo,
                                            unsigned short* __restrict__ Wec,
                                            unsigned short* __restrict__ Wes,
                                            unsigned short* __restrict__ Woc,
                                            unsigned short* __restrict__ Wos) {
    if (blockIdx.x < XBLKS) {                   // 8 f32 per thread, split parity
        int i = blockIdx.x * 256 + threadIdx.x;
        const float4* src = (const float4*)x + (size_t)i * 2;
        float4 a = src[0], b = src[1];
        uint2 e, o;
        e.x = f2bf(a.x) | (f2bf(a.z) << 16);    // g = 0,2
        e.y = f2bf(b.x) | (f2bf(b.z) << 16);    // g = 4,6
        o.x = f2bf(a.y) | (f2bf(a.w) << 16);    // g = 1,3
        o.y = f2bf(b.y) | (f2bf(b.w) << 16);    // g = 5,7
        *(uint2*)(xe + (size_t)i * 4) = e;
        *(uint2*)(xo + (size_t)i * 4) = o;
    } else {                                    // tables [160][256], f<=128 live
        int f = blockIdx.x - XBLKS;             // 0..159
        int n2 = threadIdx.x;                   // n' 0..255
        unsigned short ec = 0, es = 0, oc = 0, os = 0;
        if (f <= 128) {
            int ne = 2 * n2, no = 2 * n2 + 1;
            float we = 0.5f * (1.0f - cosf(2.0f * (float)M_PI * (float)ne / (float)FRAME_LEN));
            float wo = 0.5f * (1.0f - cosf(2.0f * (float)M_PI * (float)no / (float)FRAME_LEN));
            float ange = (float)((f * ne) & (FRAME_LEN - 1)) * (2.0f * (float)M_PI / (float)FRAME_LEN);
            float ango = (float)((f * no) & (FRAME_LEN - 1)) * (2.0f * (float)M_PI / (float)FRAME_LEN);
            float se_, ce_, so_, co_;
            sincosf(ange, &se_, &ce_);
            sincosf(ango, &so_, &co_);
            ec = (unsigned short)f2bf(ce_ * we);
            es = (unsigned short)f2bf(se_ * we);    // i = +sin*w convention
            oc = (unsigned short)f2bf(co_ * wo);
            os = (unsigned short)f2bf(so_ * wo);
        }
        Wec[f * KH + n2] = ec; Wes[f * KH + n2] = es;
        Woc[f * KH + n2] = oc; Wos[f * KH + n2] = os;
    }
}

// ------ stft via bf16 MFMA + mirror symmetry: 8 k-steps (4 even + 4 odd) ----
__global__ __launch_bounds__(256) void stft_mfma(
    const unsigned short* __restrict__ xe, const unsigned short* __restrict__ xo,
    const unsigned short* __restrict__ Wec, const unsigned short* __restrict__ Wes,
    const unsigned short* __restrict__ Woc, const unsigned short* __restrict__ Wos,
    float* __restrict__ mag)
{
    __shared__ unsigned short As[2][MT][BK];    // 32 KB, linear gload dest
    __shared__ unsigned short Bs[2][2][FT][BK]; // 16 KB (cos, sin)

    const int tid = threadIdx.x;
    // XCD swizzle: nwg=1560=8*195; 5 consecutive logical ids (one A-tile's
    // f-tiles) land on one XCD L2.
    const int logical = ((int)blockIdx.x & 7) * 195 + ((int)blockIdx.x >> 3);
    const int tileM = logical / 5;              // 0..311
    const int tileF = logical % 5;              // 0..4
    const int wid = tid >> 6;
    const int lane = tid & 63;
    const int lrow = lane & 15;
    const int lhi = lane >> 4;

    unsigned short* AsB = &As[0][0][0];
    unsigned short* BsB = &Bs[0][0][0][0];

    // k0-invariant per-lane staging sources (XOR chunk swizzle on SOURCE;
    // LDS dest linear for gload_lds; frag read applies the same XOR)
    const unsigned short* pA[2][4];
    #pragma unroll
    for (int j = 0; j < 4; j++) {
        int idx = wid * 4 + j;                  // 0..15, 8 rows each
        int row = idx * 8 + (lane >> 3);
        int m = tileM * MT + row;               // < 39936 exact
        int b = m / TFRAMES;
        int t = m - b * TFRAMES;
        int chunk = (lane & 7) ^ (row & 7);
        size_t off = (size_t)b * NSAMPH + t * (HOP / 2) + chunk * 8;
        pA[0][j] = xe + off;
        pA[1][j] = xo + off;
    }
    const unsigned short* pB[2][2];
    #pragma unroll
    for (int j = 0; j < 2; j++) {
        int i = wid * 2 + j;                    // 0..7: 0-3 cos, 4-7 sin
        int row = (i & 3) * 8 + (lane >> 3);
        int fg = tileF * FT + row;              // < 160 (padded tables)
        int chunk = (lane & 7) ^ (row & 7);
        size_t off = (size_t)fg * KH + chunk * 8;
        pB[0][j] = ((i & 4) ? Wes : Wec) + off;
        pB[1][j] = ((i & 4) ? Wos : Woc) + off;
    }

    f32x4 aC[2][2][2] = {};                     // [parity][mf][nf]
    f32x4 aS[2][2][2] = {};

    // ---- prologue: stage (parity 0, k0=0) into buf 0
    #pragma unroll
    for (int j = 0; j < 4; j++)
        gload_lds16(pA[0][j], AsB + (wid * 4 + j) * 512);
    #pragma unroll
    for (int j = 0; j < 2; j++)
        gload_lds16(pB[0][j], BsB + (wid * 2 + j) * 512);
    __syncthreads();

    int buf = 0;
    #pragma unroll
    for (int it = 0; it < 8; it++) {
        const int p = it >> 2;                  // parity phase (static: unrolled)
        // ---- issue next-chunk loads into other buffer
        if (it < 7) {
            const int pn = (it + 1) >> 2;
            const int k0 = ((it + 1) & 3) * BK;
            #pragma unroll
            for (int j = 0; j < 4; j++)
                gload_lds16(pA[pn][j] + k0, AsB + (buf ^ 1) * ASZ + (wid * 4 + j) * 512);
            #pragma unroll
            for (int j = 0; j < 2; j++)
                gload_lds16(pB[pn][j] + k0, BsB + (buf ^ 1) * BSZ + (wid * 2 + j) * 512);
        }
        // ---- compute current buffer into parity-p accumulators
        #pragma unroll
        for (int ks = 0; ks < 2; ks++) {
            short8 a[2], bc[2], bsn[2];
            const int c = (ks * 4 + lhi) ^ (lrow & 7);
            #pragma unroll
            for (int mf = 0; mf < 2; mf++)
                a[mf] = *(const short8*)(AsB + buf * ASZ +
                    (wid * 32 + mf * 16 + lrow) * BK + c * 8);
            #pragma unroll
            for (int nf = 0; nf < 2; nf++) {
                bc[nf]  = *(const short8*)(BsB + buf * BSZ +
                    (nf * 16 + lrow) * BK + c * 8);
                bsn[nf] = *(const short8*)(BsB + buf * BSZ + FT * BK +
                    (nf * 16 + lrow) * BK + c * 8);
            }
            #pragma unroll
            for (int mf = 0; mf < 2; mf++) {
                #pragma unroll
                for (int nf = 0; nf < 2; nf++) {
                    aC[p][mf][nf] = __builtin_amdgcn_mfma_f32_16x16x32_bf16(
                        a[mf], bc[nf], aC[p][mf][nf], 0, 0, 0);
                    aS[p][mf][nf] = __builtin_amdgcn_mfma_f32_16x16x32_bf16(
                        a[mf], bsn[nf], aS[p][mf][nf], 0, 0, 0);
                }
            }
        }
        __syncthreads();                        // next buffer landed; reads done
        buf ^= 1;
    }

    // ---- epilogue: f (<=128) direct, 256-f mirror; float4 over 4 t
    #pragma unroll
    for (int mf = 0; mf < 2; mf++) {
        int m0 = tileM * MT + wid * 32 + mf * 16 + lhi * 4;
        int b = m0 / TFRAMES;
        int t = m0 - b * TFRAMES;               // %4==0, run stays in batch
        #pragma unroll
        for (int nf = 0; nf < 2; nf++) {
            int f = tileF * FT + nf * 16 + lrow;
            float4 od, om;
            #pragma unroll
            for (int q = 0; q < 4; q++) {
                const float Ce = aC[0][mf][nf][q], Co = aC[1][mf][nf][q];
                const float Se = aS[0][mf][nf][q], So = aS[1][mf][nf][q];
                const float rd = Ce + Co, id = Se + So;
                const float rm = Ce - Co, im = So - Se;
                (&od.x)[q] = sqrtf(rd * rd + id * id);
                (&om.x)[q] = sqrtf(rm * rm + im * im);
            }
            if (f <= 128)
                *(float4*)(mag + ((size_t)b * NFREQ + f) * TFRAMES + t) = od;
            if (f <= 127)
                *(float4*)(mag + ((size_t)b * NFREQ + (256 - f)) * TFRAMES + t) = om;
        }
    }
}

// ------------------------------------------- normalize: warp-per-row, f4 ----
__global__ __launch_bounds__(256) void normalize(const float* __restrict__ mag,
                                                 float* __restrict__ feat)
{
    const int row = blockIdx.x * 4 + (threadIdx.x >> 6);    // b*NFREQ+f
    const int lane = threadIdx.x & 63;
    const float* mp = mag + (size_t)row * TFRAMES;

    float4 v[3];
    float sum = 0.f;
    #pragma unroll
    for (int i = 0; i < 3; i++) {
        int c4 = lane + i * 64;                 // 156 float4 per row
        if (c4 < TFRAMES / 4) {
            float4 t = *(const float4*)(mp + c4 * 4);
            t.x = fmaxf(t.x, EPS); t.y = fmaxf(t.y, EPS);
            t.z = fmaxf(t.z, EPS); t.w = fmaxf(t.w, EPS);
            v[i] = t;
            sum += (t.x + t.y) + (t.z + t.w);
        } else {
            v[i] = make_float4(0.f, 0.f, 0.f, 0.f);
        }
    }
    #pragma unroll
    for (int off = 1; off < 64; off <<= 1) sum += __shfl_xor(sum, off, 64);
    const float mean = sum * (1.0f / (float)TFRAMES);

    float ssd = 0.f;
    #pragma unroll
    for (int i = 0; i < 3; i++) {
        int c4 = lane + i * 64;
        if (c4 < TFRAMES / 4) {
            float dx = v[i].x - mean, dy = v[i].y - mean;
            float dz = v[i].z - mean, dw = v[i].w - mean;
            ssd += (dx * dx + dy * dy) + (dz * dz + dw * dw);
        }
    }
    #pragma unroll
    for (int off = 1; off < 64; off <<= 1) ssd += __shfl_xor(ssd, off, 64);
    const float stdv = sqrtf(ssd * (1.0f / (float)(TFRAMES - 1)));
    const float inv = 1.0f / (stdv + EPS);

    float* fp = feat + (size_t)row * TFRAMES;
    #pragma unroll
    for (int i = 0; i < 3; i++) {
        int c4 = lane + i * 64;
        if (c4 < TFRAMES / 4) {
            float4 o;
            o.x = (v[i].x - mean) * inv; o.y = (v[i].y - mean) * inv;
            o.z = (v[i].z - mean) * inv; o.w = (v[i].w - mean) * inv;
            *(float4*)(fp + c4 * 4) = o;
        }
    }
}

// ---------------------------------------------------------------- launch ----
extern "C" void kernel_launch(void* const* d_in, const int* in_sizes, int n_in,
                              void* d_out, int out_size, void* d_ws, size_t ws_size,
                              hipStream_t stream) {
    const float* x = (const float*)d_in[0];
    unsigned short* Wec = (unsigned short*)d_ws;            // [160][256] bf16
    unsigned short* Wes = Wec + 160 * KH;
    unsigned short* Woc = Wes + 160 * KH;
    unsigned short* Wos = Woc + 160 * KH;
    unsigned short* xe  = Wos + 160 * KH;                   // [64][80000] bf16
    unsigned short* xo  = xe + (size_t)NBATCH * NSAMPH;     // [64][80000] bf16
    float* mag  = (float*)d_out;                            // [64][257][624]
    float* feat = mag + (size_t)NBATCH * NFREQ * TFRAMES;

    prep<<<XBLKS + 160, 256, 0, stream>>>(x, xe, xo, Wec, Wes, Woc, Wos);

    // 312 M-tiles x 5 F-tiles, linearized + XCD-swizzled in-kernel
    stft_mfma<<<312 * 5, 256, 0, stream>>>(xe, xo, Wec, Wes, Woc, Wos, mag);

    normalize<<<NBATCH * NFREQ / 4, 256, 0, stream>>>(mag, feat);
}